// Round 1
// baseline (866.729 us; speedup 1.0000x reference)
//
#include <hip/hip_runtime.h>

#define NN 50000
#define EE 1600000
#define MM 2
#define DIN 2000
#define H1 500
#define LAT 128
#define DECF 64
#define HIDF 64
#define NCF 16
#define KTOT (MM*DIN)        // 4000
#define KSTEPS (KTOT/32)     // 125
#define EPSBN 1e-5f

typedef float f32x4 __attribute__((ext_vector_type(4)));
typedef short short8v __attribute__((ext_vector_type(8)));

__device__ __forceinline__ unsigned int pkbf(float a, float b){
  unsigned int ua = __float_as_uint(a), ub = __float_as_uint(b);
  ua = (ua + 0x7FFFu + ((ua>>16)&1u)) >> 16;
  ub = (ub + 0x7FFFu + ((ub>>16)&1u)) & 0xFFFF0000u;
  return ua | ub;
}

// ---- precompute: BN-folded affine collapse ----
__global__ void prep0(const float* b1,const float* g1,const float* be1,const float* m1,const float* v1,
                      const float* b2,const float* g2,const float* be2,const float* m2,const float* v2,
                      float* a1,float* c1,float* a2,float* c2){
  for (int i = threadIdx.x; i < MM*H1; i += blockDim.x){
    float a = g1[i]*rsqrtf(v1[i]+EPSBN);
    a1[i]=a; c1[i]=(b1[i]-m1[i])*a+be1[i];
  }
  for (int i = threadIdx.x; i < MM*LAT; i += blockDim.x){
    float a = g2[i]*rsqrtf(v2[i]+EPSBN);
    a2[i]=a; c2[i]=(b2[i]-m2[i])*a+be2[i];
  }
}

// T[m][k][d] = sum_l W2[m][k][l]*a2[m][l]*Wd[m][l][d]
__global__ void prep1(const float* __restrict__ W2,const float* __restrict__ Wd,
                      const float* __restrict__ a2, float* __restrict__ T){
  int g = blockIdx.x*blockDim.x + threadIdx.x;
  if (g >= MM*H1*DECF) return;
  int d = g & 63; int mk = g >> 6; int k = mk % H1; int m = mk / H1;
  const float* w2 = W2 + (size_t)(m*H1 + k)*LAT;
  const float* wd = Wd + (size_t)m*LAT*DECF + d;
  const float* a  = a2 + m*LAT;
  float acc = 0.f;
  for (int l = 0; l < LAT; ++l) acc += w2[l]*a[l]*wd[(size_t)l*DECF];
  T[g] = acc;
}

// Weff[m][i][d] = 0.5 * sum_k W1[m][i][k]*a1[m][k]*T[m][k][d]; store bf16 in B-fragment order
__global__ void prep2(const float* __restrict__ W1,const float* __restrict__ a1,
                      const float* __restrict__ T, unsigned short* __restrict__ WB){
  int g = blockIdx.x*blockDim.x + threadIdx.x;
  if (g >= MM*DIN*DECF) return;
  int d = g & 63; int mi = g >> 6; int i = mi % DIN; int m = mi / DIN;
  const float* w1 = W1 + (size_t)(m*DIN + i)*H1;
  const float* a  = a1 + m*H1;
  const float* t  = T + (size_t)m*H1*DECF + d;
  float acc = 0.f;
  for (int k = 0; k < H1; ++k) acc += w1[k]*a[k]*t[(size_t)k*DECF];
  acc *= 0.5f;
  unsigned int u = __float_as_uint(acc);
  unsigned short bf = (unsigned short)((u + 0x7FFFu + ((u>>16)&1u)) >> 16);
  int kc = m*DIN + i;              // combined K in [0,4000)
  int s = kc >> 5, kl = kc & 31;
  int laneB = ((kl>>3)<<4) | (d & 15);
  int t4 = d >> 4;
  WB[((size_t)((s*4 + t4)*64 + laneB))*8 + (kl & 7)] = bf;
}

// cbar[d] = 0.5 * sum_m ( c1@T + c2@Wd + bd )
__global__ void prep3(const float* __restrict__ c1,const float* __restrict__ c2,
                      const float* __restrict__ T,const float* __restrict__ Wd,
                      const float* __restrict__ bd, float* __restrict__ cbar){
  int d = threadIdx.x;
  if (d >= DECF) return;
  float s = 0.f;
  for (int m = 0; m < MM; ++m){
    float sm = bd[m*DECF + d];
    const float* t = T + (size_t)m*H1*DECF + d;
    const float* c1m = c1 + m*H1;
    for (int k = 0; k < H1; ++k) sm += c1m[k]*t[(size_t)k*DECF];
    const float* wd = Wd + (size_t)m*LAT*DECF + d;
    const float* c2m = c2 + m*LAT;
    for (int l = 0; l < LAT; ++l) sm += c2m[l]*wd[(size_t)l*DECF];
    s += sm;
  }
  cbar[d] = 0.5f*s;
}

// ---- graph prep ----
__global__ void degk(const int* __restrict__ src,const int* __restrict__ dst,
                     int* __restrict__ dout,int* __restrict__ din){
  int e = blockIdx.x*blockDim.x + threadIdx.x;
  if (e >= EE) return;
  atomicAdd(&dout[src[e]], 1);
  atomicAdd(&din[dst[e]], 1);
}

__global__ void normk(const int* __restrict__ dout,const int* __restrict__ din,
                      float* __restrict__ csrc,float* __restrict__ cdst){
  int n = blockIdx.x*blockDim.x + threadIdx.x;
  if (n >= NN) return;
  int a = dout[n]; if (a < 1) a = 1;
  int b = din[n];  if (b < 1) b = 1;
  csrc[n] = rsqrtf((float)a);
  cdst[n] = rsqrtf((float)b);
}

__global__ __launch_bounds__(1024) void scan1(const int* __restrict__ deg, int* __restrict__ rp,
                      int* __restrict__ bsum, int n){
  __shared__ int sm[1024];
  int i = blockIdx.x*1024 + threadIdx.x;
  int v = (i < n) ? deg[i] : 0;
  sm[threadIdx.x] = v; __syncthreads();
  for (int off=1; off<1024; off<<=1){
    int t = (threadIdx.x >= off) ? sm[threadIdx.x-off] : 0;
    __syncthreads();
    sm[threadIdx.x] += t;
    __syncthreads();
  }
  if (i < n) rp[i] = sm[threadIdx.x] - v;
  if (threadIdx.x == 1023) bsum[blockIdx.x] = sm[1023];
}

__global__ void scan2(const int* __restrict__ bsum, int* __restrict__ boff, int nb,
                      int* __restrict__ rp, int n){
  if (threadIdx.x==0 && blockIdx.x==0){
    int run = 0;
    for (int b=0;b<nb;b++){ boff[b]=run; run+=bsum[b]; }
    rp[n] = run;
  }
}

__global__ void scan3(int* __restrict__ rp, const int* __restrict__ boff, int n){
  int i = blockIdx.x*blockDim.x + threadIdx.x;
  if (i < n) rp[i] += boff[i>>10];
}

__global__ void scatk(const int* __restrict__ src,const int* __restrict__ dst,
                      const int* __restrict__ rp,int* __restrict__ cur,int* __restrict__ ss){
  int e = blockIdx.x*blockDim.x + threadIdx.x;
  if (e >= EE) return;
  int d = dst[e];
  int p = rp[d] + atomicAdd(&cur[d], 1);
  ss[p] = src[e];
}

// ---- main GEMM: nf_pre[n][d] = (0.5*sum_m x_m[n,:]@Weff_m[:,d] + cbar[d]) * c_src[n] ----
__global__ __launch_bounds__(256) void gemm_nf(
    const float* __restrict__ x, const short8v* __restrict__ WB,
    const float* __restrict__ cbar, const float* __restrict__ csrc,
    float* __restrict__ nfpre)
{
  const int lane = threadIdx.x & 63;
  const int wave = threadIdx.x >> 6;
  const int n0 = blockIdx.x*64 + wave*16;
  const int r = lane & 15;
  const int kg = (lane >> 4) << 3;             // k-slot base: 0,8,16,24
  int row = n0 + r; if (row > NN-1) row = NN-1;
  const float* xrow = x + (size_t)row * DIN;

  f32x4 acc0 = {0.f,0.f,0.f,0.f}, acc1 = acc0, acc2 = acc0, acc3 = acc0;

  f32x4 A0c, A1c; short8v B0c, B1c, B2c, B3c;
  {
    const float* p = xrow + kg;                // s=0 always in modality 0
    A0c = *(const f32x4*)p; A1c = *(const f32x4*)(p+4);
    const short8v* bp = WB + lane;
    B0c = bp[0]; B1c = bp[64]; B2c = bp[128]; B3c = bp[192];
  }
  for (int s = 0; s < KSTEPS-1; ++s){
    f32x4 A0n, A1n; short8v B0n, B1n, B2n, B3n;
    {
      int kr = (s+1)*32 + kg;
      const float* p = (kr < DIN) ? (xrow + kr)
                                  : (xrow + (size_t)(NN-1)*DIN + kr); // = x+(NN+row)*DIN+(kr-DIN)
      A0n = *(const f32x4*)p; A1n = *(const f32x4*)(p+4);
      const short8v* bp = WB + (size_t)(s+1)*256 + lane;
      B0n = bp[0]; B1n = bp[64]; B2n = bp[128]; B3n = bp[192];
    }
    union { short8v v; unsigned int u[4]; } AF;
    AF.u[0]=pkbf(A0c[0],A0c[1]); AF.u[1]=pkbf(A0c[2],A0c[3]);
    AF.u[2]=pkbf(A1c[0],A1c[1]); AF.u[3]=pkbf(A1c[2],A1c[3]);
    acc0 = __builtin_amdgcn_mfma_f32_16x16x32_bf16(AF.v, B0c, acc0, 0,0,0);
    acc1 = __builtin_amdgcn_mfma_f32_16x16x32_bf16(AF.v, B1c, acc1, 0,0,0);
    acc2 = __builtin_amdgcn_mfma_f32_16x16x32_bf16(AF.v, B2c, acc2, 0,0,0);
    acc3 = __builtin_amdgcn_mfma_f32_16x16x32_bf16(AF.v, B3c, acc3, 0,0,0);
    A0c=A0n; A1c=A1n; B0c=B0n; B1c=B1n; B2c=B2n; B3c=B3n;
  }
  {
    union { short8v v; unsigned int u[4]; } AF;
    AF.u[0]=pkbf(A0c[0],A0c[1]); AF.u[1]=pkbf(A0c[2],A0c[3]);
    AF.u[2]=pkbf(A1c[0],A1c[1]); AF.u[3]=pkbf(A1c[2],A1c[3]);
    acc0 = __builtin_amdgcn_mfma_f32_16x16x32_bf16(AF.v, B0c, acc0, 0,0,0);
    acc1 = __builtin_amdgcn_mfma_f32_16x16x32_bf16(AF.v, B1c, acc1, 0,0,0);
    acc2 = __builtin_amdgcn_mfma_f32_16x16x32_bf16(AF.v, B2c, acc2, 0,0,0);
    acc3 = __builtin_amdgcn_mfma_f32_16x16x32_bf16(AF.v, B3c, acc3, 0,0,0);
  }
  const int rg = (lane >> 4) << 2;             // D row group: 0,4,8,12
  float cb0 = cbar[r], cb1 = cbar[16+r], cb2 = cbar[32+r], cb3 = cbar[48+r];
  #pragma unroll
  for (int rr = 0; rr < 4; ++rr){
    int rowD = n0 + rg + rr;
    if (rowD < NN){
      float cs = csrc[rowD];
      float* o = nfpre + (size_t)rowD*64 + r;
      o[0]  = (acc0[rr] + cb0)*cs;
      o[16] = (acc1[rr] + cb1)*cs;
      o[32] = (acc2[rr] + cb2)*cs;
      o[48] = (acc3[rr] + cb3)*cs;
    }
  }
}

// ---- CSR gather-sum: out[n][lane] = sum_{e in in(n)} feat[src_e][lane] ----
__global__ __launch_bounds__(256) void gath(const float* __restrict__ feat,const int* __restrict__ rp,
                     const int* __restrict__ ss, float* __restrict__ out){
  int wid = (blockIdx.x*blockDim.x + threadIdx.x) >> 6;
  int lane = threadIdx.x & 63;
  if (wid >= NN) return;
  int beg = rp[wid], end = rp[wid+1];
  float s = 0.f;
  int e = beg;
  for (; e + 4 <= end; e += 4){
    int i0=ss[e], i1=ss[e+1], i2=ss[e+2], i3=ss[e+3];
    float f0=feat[(size_t)i0*64+lane], f1=feat[(size_t)i1*64+lane],
          f2=feat[(size_t)i2*64+lane], f3=feat[(size_t)i3*64+lane];
    s += f0+f1+f2+f3;
  }
  for (; e < end; ++e) s += feat[(size_t)ss[e]*64+lane];
  out[(size_t)wid*64+lane] = s;
}

// h_pre[n][j] = relu(c_dst[n]*(g@Wg1)[j] + bg1[j]) * c_src[n]
__global__ __launch_bounds__(256) void dense1(const float* __restrict__ gat,const float* __restrict__ Wg1,
                       const float* __restrict__ bg1,const float* __restrict__ csrc,
                       const float* __restrict__ cdst,float* __restrict__ hpre){
  __shared__ float W[64*64];
  for (int i = threadIdx.x; i < 64*64; i += 256) W[i] = Wg1[i];
  __syncthreads();
  int wave = threadIdx.x >> 6, lane = threadIdx.x & 63;
  int n = blockIdx.x*4 + wave;
  if (n >= NN) return;
  float g = gat[(size_t)n*64 + lane];
  float acc = 0.f;
  #pragma unroll
  for (int k = 0; k < 64; ++k)
    acc += __shfl(g, k, 64) * W[k*64 + lane];
  float h = fmaxf(cdst[n]*acc + bg1[lane], 0.f) * csrc[n];
  hpre[(size_t)n*64 + lane] = h;
}

// score[n][c] = c_dst[n]*(g@Wg2)[c] + bg2[c]
__global__ __launch_bounds__(256) void dense2(const float* __restrict__ gat,const float* __restrict__ Wg2,
                       const float* __restrict__ bg2,const float* __restrict__ cdst,
                       float* __restrict__ score){
  __shared__ float W[64*16];
  for (int i = threadIdx.x; i < 64*16; i += 256) W[i] = Wg2[i];
  __syncthreads();
  int wave = threadIdx.x >> 6, lane = threadIdx.x & 63;
  int n = blockIdx.x*4 + wave;
  if (n >= NN) return;
  float g = gat[(size_t)n*64 + lane];
  int c = lane & 15;
  float acc = 0.f;
  #pragma unroll
  for (int k = 0; k < 64; ++k)
    acc += __shfl(g, k, 64) * W[k*16 + c];
  if (lane < 16) score[(size_t)n*16 + lane] = cdst[n]*acc + bg2[lane];
}

extern "C" void kernel_launch(void* const* d_in, const int* in_sizes, int n_in,
                              void* d_out, int out_size, void* d_ws, size_t ws_size,
                              hipStream_t stream){
  const float* x   = (const float*)d_in[0];
  const int* src   = (const int*)d_in[1];
  const int* dst   = (const int*)d_in[2];
  const float* W1  = (const float*)d_in[3];
  const float* b1  = (const float*)d_in[4];
  const float* g1  = (const float*)d_in[5];
  const float* be1 = (const float*)d_in[6];
  const float* m1  = (const float*)d_in[7];
  const float* v1  = (const float*)d_in[8];
  const float* W2  = (const float*)d_in[9];
  const float* b2  = (const float*)d_in[10];
  const float* g2  = (const float*)d_in[11];
  const float* be2 = (const float*)d_in[12];
  const float* m2  = (const float*)d_in[13];
  const float* v2  = (const float*)d_in[14];
  const float* Wd  = (const float*)d_in[15];
  const float* bd  = (const float*)d_in[16];
  const float* Wg1 = (const float*)d_in[17];
  const float* bg1 = (const float*)d_in[18];
  const float* Wg2 = (const float*)d_in[19];
  const float* bg2 = (const float*)d_in[20];
  float* score = (float*)d_out;

  char* w = (char*)d_ws;
  size_t off = 0;
  auto alc = [&](size_t b){ size_t c = off; off += (b + 255) & ~(size_t)255; return c; };
  size_t o_dout = alc((size_t)NN*4), o_din = alc((size_t)NN*4), o_cur = alc((size_t)NN*4);
  size_t o_rp  = alc((size_t)(NN+1)*4), o_bsum = alc(256*4), o_boff = alc(256*4);
  size_t o_csrc = alc((size_t)NN*4), o_cdst = alc((size_t)NN*4);
  size_t o_a1 = alc((size_t)MM*H1*4), o_c1 = alc((size_t)MM*H1*4);
  size_t o_a2 = alc((size_t)MM*LAT*4), o_c2 = alc((size_t)MM*LAT*4);
  size_t o_T = alc((size_t)MM*H1*DECF*4), o_cbar = alc(DECF*4);
  size_t o_WB = alc((size_t)MM*DIN*DECF*2);
  size_t o_ss = alc((size_t)EE*4);
  size_t o_nf = alc((size_t)NN*64*4);   // nf_pre, later reused as h_pre
  size_t o_g  = alc((size_t)NN*64*4);   // gather1, later reused as gather2

  int* dout = (int*)(w+o_dout); int* din = (int*)(w+o_din); int* cur = (int*)(w+o_cur);
  int* rp = (int*)(w+o_rp); int* bsum = (int*)(w+o_bsum); int* boff = (int*)(w+o_boff);
  float* csrc = (float*)(w+o_csrc); float* cdst = (float*)(w+o_cdst);
  float* a1 = (float*)(w+o_a1); float* c1 = (float*)(w+o_c1);
  float* a2 = (float*)(w+o_a2); float* c2 = (float*)(w+o_c2);
  float* T = (float*)(w+o_T); float* cbar = (float*)(w+o_cbar);
  unsigned short* WBu = (unsigned short*)(w+o_WB);
  int* ss = (int*)(w+o_ss);
  float* nf = (float*)(w+o_nf); float* gbuf = (float*)(w+o_g);

  hipMemsetAsync(dout, 0, (size_t)NN*4, stream);
  hipMemsetAsync(din, 0, (size_t)NN*4, stream);
  hipMemsetAsync(cur, 0, (size_t)NN*4, stream);

  prep0<<<1,256,0,stream>>>(b1,g1,be1,m1,v1,b2,g2,be2,m2,v2,a1,c1,a2,c2);
  prep1<<<(MM*H1*DECF+255)/256,256,0,stream>>>(W2,Wd,a2,T);
  prep2<<<(MM*DIN*DECF+255)/256,256,0,stream>>>(W1,a1,T,WBu);
  prep3<<<1,64,0,stream>>>(c1,c2,T,Wd,bd,cbar);

  degk<<<(EE+255)/256,256,0,stream>>>(src,dst,dout,din);
  normk<<<(NN+255)/256,256,0,stream>>>(dout,din,csrc,cdst);
  int nb = (NN+1023)/1024;
  scan1<<<nb,1024,0,stream>>>(din,rp,bsum,NN);
  scan2<<<1,1,0,stream>>>(bsum,boff,nb,rp,NN);
  scan3<<<(NN+255)/256,256,0,stream>>>(rp,boff,NN);
  scatk<<<(EE+255)/256,256,0,stream>>>(src,dst,rp,cur,ss);

  gemm_nf<<<(NN+63)/64,256,0,stream>>>(x,(const short8v*)(w+o_WB),cbar,csrc,nf);

  gath<<<(NN*64+255)/256,256,0,stream>>>(nf,rp,ss,gbuf);
  dense1<<<(NN+3)/4,256,0,stream>>>(gbuf,Wg1,bg1,csrc,cdst,nf);
  gath<<<(NN*64+255)/256,256,0,stream>>>(nf,rp,ss,gbuf);
  dense2<<<(NN+3)/4,256,0,stream>>>(gbuf,Wg2,bg2,cdst,score);
}

// Round 2
// 857.711 us; speedup vs baseline: 1.0105x; 1.0105x over previous
//
#include <hip/hip_runtime.h>

#define NN 50000
#define EE 1600000
#define MM 2
#define DIN 2000
#define H1 500
#define LAT 128
#define DECF 64
#define KTOT (MM*DIN)        // 4000
#define KSTEPS (KTOT/32)     // 125
#define EPSBN 1e-5f

typedef float f32x4 __attribute__((ext_vector_type(4)));
typedef short short8v __attribute__((ext_vector_type(8)));

__device__ __forceinline__ unsigned int pkbf(float a, float b){
  unsigned int ua = __float_as_uint(a), ub = __float_as_uint(b);
  ua = (ua + 0x7FFFu + ((ua>>16)&1u)) >> 16;
  ub = (ub + 0x7FFFu + ((ub>>16)&1u)) & 0xFFFF0000u;
  return ua | ub;
}

// ---- prepA: T[m][k][d] = sum_l W2[m][k][l]*a2[m][l]*Wd[m][l][d], a2 inline ----
__global__ __launch_bounds__(256) void prepA(const float* __restrict__ W2,const float* __restrict__ Wd,
                      const float* __restrict__ g2,const float* __restrict__ v2,
                      float* __restrict__ T){
  __shared__ float a2[LAT];
  int m = (blockIdx.x*4) / H1;              // 4 mk per block, never crosses m
  if (threadIdx.x < LAT)
    a2[threadIdx.x] = g2[m*LAT+threadIdx.x]*rsqrtf(v2[m*LAT+threadIdx.x]+EPSBN);
  __syncthreads();
  int g = blockIdx.x*256 + threadIdx.x;     // grid exact: 64000/256 = 250
  int d = g & 63; int mk = g >> 6; int k = mk % H1;
  const float* w2 = W2 + (size_t)(m*H1 + k)*LAT;
  const float* wd = Wd + (size_t)m*LAT*DECF + d;
  float acc = 0.f;
  for (int l = 0; l < LAT; ++l) acc += w2[l]*a2[l]*wd[(size_t)l*DECF];
  T[g] = acc;
}

// ---- prepB: Weff (bf16, B-fragment order), a1 inline ----
__global__ __launch_bounds__(256) void prepB(const float* __restrict__ W1,const float* __restrict__ g1,
                      const float* __restrict__ v1,const float* __restrict__ T,
                      unsigned short* __restrict__ WB){
  __shared__ float a1[H1];
  int m = (blockIdx.x*4) / DIN;             // 4 mi per block, never crosses m
  for (int k = threadIdx.x; k < H1; k += 256)
    a1[k] = g1[m*H1+k]*rsqrtf(v1[m*H1+k]+EPSBN);
  __syncthreads();
  int g = blockIdx.x*256 + threadIdx.x;     // grid exact: 256000/256 = 1000
  int d = g & 63; int mi = g >> 6; int i = mi % DIN;
  const float* w1 = W1 + (size_t)(m*DIN + i)*H1;
  const float* t  = T + (size_t)m*H1*DECF + d;
  float acc = 0.f;
  for (int k = 0; k < H1; ++k) acc += w1[k]*a1[k]*t[(size_t)k*DECF];
  acc *= 0.5f;
  unsigned int u = __float_as_uint(acc);
  unsigned short bf = (unsigned short)((u + 0x7FFFu + ((u>>16)&1u)) >> 16);
  int kc = m*DIN + i;
  int s = kc >> 5, kl = kc & 31;
  int laneB = ((kl>>3)<<4) | (d & 15);
  int t4 = d >> 4;
  WB[((size_t)((s*4 + t4)*64 + laneB))*8 + (kl & 7)] = bf;
}

// ---- prepC: cbar[d] = 0.5 * sum_m ( c1@T + c2@Wd + bd ), c1/c2 inline ----
__global__ void prepC(const float* __restrict__ b1,const float* __restrict__ g1,const float* __restrict__ be1,
                      const float* __restrict__ m1,const float* __restrict__ v1,
                      const float* __restrict__ b2,const float* __restrict__ g2,const float* __restrict__ be2,
                      const float* __restrict__ m2,const float* __restrict__ v2,
                      const float* __restrict__ T,const float* __restrict__ Wd,
                      const float* __restrict__ bd, float* __restrict__ cbar){
  int d = threadIdx.x;
  if (d >= DECF) return;
  float s = 0.f;
  for (int m = 0; m < MM; ++m){
    float sm = bd[m*DECF + d];
    const float* t = T + (size_t)m*H1*DECF + d;
    for (int k = 0; k < H1; ++k){
      float a = g1[m*H1+k]*rsqrtf(v1[m*H1+k]+EPSBN);
      float c = (b1[m*H1+k]-m1[m*H1+k])*a + be1[m*H1+k];
      sm += c*t[(size_t)k*DECF];
    }
    const float* wd = Wd + (size_t)m*LAT*DECF + d;
    for (int l = 0; l < LAT; ++l){
      float a = g2[m*LAT+l]*rsqrtf(v2[m*LAT+l]+EPSBN);
      float c = (b2[m*LAT+l]-m2[m*LAT+l])*a + be2[m*LAT+l];
      sm += c*wd[(size_t)l*DECF];
    }
    s += sm;
  }
  cbar[d] = 0.5f*s;
}

// ---- graph prep ----
__global__ void degk(const int* __restrict__ src,const int* __restrict__ dst,
                     int* __restrict__ dout,int* __restrict__ din){
  int e = blockIdx.x*blockDim.x + threadIdx.x;
  if (e >= EE) return;
  atomicAdd(&dout[src[e]], 1);
  atomicAdd(&din[dst[e]], 1);
}

__global__ __launch_bounds__(1024) void scan1(const int* __restrict__ deg, int* __restrict__ rp,
                      int* __restrict__ bsum, int n){
  __shared__ int sm[1024];
  int i = blockIdx.x*1024 + threadIdx.x;
  int v = (i < n) ? deg[i] : 0;
  sm[threadIdx.x] = v; __syncthreads();
  for (int off=1; off<1024; off<<=1){
    int t = (threadIdx.x >= off) ? sm[threadIdx.x-off] : 0;
    __syncthreads();
    sm[threadIdx.x] += t;
    __syncthreads();
  }
  if (i < n) rp[i] = sm[threadIdx.x] - v;
  if (threadIdx.x == 1023) bsum[blockIdx.x] = sm[1023];
}

// scan block-offset add + rp[NN] + degree-norm coefficients, fused
__global__ void scan3n(int* __restrict__ rp, const int* __restrict__ bsum,
                       const int* __restrict__ dout, const int* __restrict__ din,
                       float* __restrict__ csrc, float* __restrict__ cdst){
  int i = blockIdx.x*blockDim.x + threadIdx.x;
  if (i >= NN) return;
  int b = i >> 10;
  int base = 0;
  for (int j = 0; j < b; ++j) base += bsum[j];
  rp[i] += base;
  if (i == NN-1) rp[NN] = EE;               // total in-degree == E
  int a = dout[i]; if (a < 1) a = 1;
  int dd = din[i]; if (dd < 1) dd = 1;
  csrc[i] = rsqrtf((float)a);
  cdst[i] = rsqrtf((float)dd);
}

__global__ void scatk(const int* __restrict__ src,const int* __restrict__ dst,
                      const int* __restrict__ rp,int* __restrict__ cur,int* __restrict__ ss){
  int e = blockIdx.x*blockDim.x + threadIdx.x;
  if (e >= EE) return;
  int d = dst[e];
  int p = rp[d] + atomicAdd(&cur[d], 1);
  ss[p] = src[e];
}

// ---- main GEMM: nf[n][d] = (0.5*sum_m x_m[n,:]@Weff_m[:,d] + cbar[d]) * c_src[n] ----
__global__ __launch_bounds__(256) void gemm_nf(
    const float* __restrict__ x, const short8v* __restrict__ WB,
    const float* __restrict__ cbar, const float* __restrict__ csrc,
    float* __restrict__ nfpre)
{
  const int lane = threadIdx.x & 63;
  const int wave = threadIdx.x >> 6;
  const int n0 = blockIdx.x*64 + wave*16;
  const int r = lane & 15;
  const int kg = (lane >> 4) << 3;             // k-slot base: 0,8,16,24
  int row = n0 + r; if (row > NN-1) row = NN-1;
  const float* xrow = x + (size_t)row * DIN;

  f32x4 acc0 = {0.f,0.f,0.f,0.f}, acc1 = acc0, acc2 = acc0, acc3 = acc0;

  f32x4 A0c, A1c; short8v B0c, B1c, B2c, B3c;
  {
    const float* p = xrow + kg;                // s=0 always in modality 0
    A0c = *(const f32x4*)p; A1c = *(const f32x4*)(p+4);
    const short8v* bp = WB + lane;
    B0c = bp[0]; B1c = bp[64]; B2c = bp[128]; B3c = bp[192];
  }
  for (int s = 0; s < KSTEPS-1; ++s){
    f32x4 A0n, A1n; short8v B0n, B1n, B2n, B3n;
    {
      int kr = (s+1)*32 + kg;
      const float* p = (kr < DIN) ? (xrow + kr)
                                  : (xrow + (size_t)(NN-1)*DIN + kr);
      A0n = *(const f32x4*)p; A1n = *(const f32x4*)(p+4);
      const short8v* bp = WB + (size_t)(s+1)*256 + lane;
      B0n = bp[0]; B1n = bp[64]; B2n = bp[128]; B3n = bp[192];
    }
    union { short8v v; unsigned int u[4]; } AF;
    AF.u[0]=pkbf(A0c[0],A0c[1]); AF.u[1]=pkbf(A0c[2],A0c[3]);
    AF.u[2]=pkbf(A1c[0],A1c[1]); AF.u[3]=pkbf(A1c[2],A1c[3]);
    acc0 = __builtin_amdgcn_mfma_f32_16x16x32_bf16(AF.v, B0c, acc0, 0,0,0);
    acc1 = __builtin_amdgcn_mfma_f32_16x16x32_bf16(AF.v, B1c, acc1, 0,0,0);
    acc2 = __builtin_amdgcn_mfma_f32_16x16x32_bf16(AF.v, B2c, acc2, 0,0,0);
    acc3 = __builtin_amdgcn_mfma_f32_16x16x32_bf16(AF.v, B3c, acc3, 0,0,0);
    A0c=A0n; A1c=A1n; B0c=B0n; B1c=B1n; B2c=B2n; B3c=B3n;
  }
  {
    union { short8v v; unsigned int u[4]; } AF;
    AF.u[0]=pkbf(A0c[0],A0c[1]); AF.u[1]=pkbf(A0c[2],A0c[3]);
    AF.u[2]=pkbf(A1c[0],A1c[1]); AF.u[3]=pkbf(A1c[2],A1c[3]);
    acc0 = __builtin_amdgcn_mfma_f32_16x16x32_bf16(AF.v, B0c, acc0, 0,0,0);
    acc1 = __builtin_amdgcn_mfma_f32_16x16x32_bf16(AF.v, B1c, acc1, 0,0,0);
    acc2 = __builtin_amdgcn_mfma_f32_16x16x32_bf16(AF.v, B2c, acc2, 0,0,0);
    acc3 = __builtin_amdgcn_mfma_f32_16x16x32_bf16(AF.v, B3c, acc3, 0,0,0);
  }
  const int rg = (lane >> 4) << 2;
  float cb0 = cbar[r], cb1 = cbar[16+r], cb2 = cbar[32+r], cb3 = cbar[48+r];
  #pragma unroll
  for (int rr = 0; rr < 4; ++rr){
    int rowD = n0 + rg + rr;
    if (rowD < NN){
      float cs = csrc[rowD];
      float* o = nfpre + (size_t)rowD*64 + r;
      o[0]  = (acc0[rr] + cb0)*cs;
      o[16] = (acc1[rr] + cb1)*cs;
      o[32] = (acc2[rr] + cb2)*cs;
      o[48] = (acc3[rr] + cb3)*cs;
    }
  }
}

// ---- fused gather + dense1: hpre[n][j] = relu(cdst[n]*(agg@Wg1)[j]+bg1[j])*csrc[n] ----
__global__ __launch_bounds__(256) void fgd1(const float* __restrict__ nf,const int* __restrict__ rp,
                      const int* __restrict__ ss,const float* __restrict__ Wg1,
                      const float* __restrict__ bg1,const float* __restrict__ csrc,
                      const float* __restrict__ cdst,float* __restrict__ hpre){
  __shared__ float W[64*64];
  for (int i = threadIdx.x; i < 64*64; i += 256) W[i] = Wg1[i];
  __syncthreads();
  int wave = threadIdx.x >> 6, lane = threadIdx.x & 63;
  int n = blockIdx.x*4 + wave;
  if (n >= NN) return;
  int q = lane >> 4, c0 = (lane & 15)*4;
  int beg = rp[n], end = rp[n+1];
  f32x4 s4 = {0.f,0.f,0.f,0.f};
  int e = beg + q;
  for (; e + 4 < end; e += 8){
    int i0 = ss[e], i1 = ss[e+4];
    f32x4 f0 = *(const f32x4*)(nf + (size_t)i0*64 + c0);
    f32x4 f1 = *(const f32x4*)(nf + (size_t)i1*64 + c0);
    s4 += f0 + f1;
  }
  if (e < end)
    s4 += *(const f32x4*)(nf + (size_t)ss[e]*64 + c0);
  // reduce across the 4 q-groups
  s4.x += __shfl_xor(s4.x,16); s4.y += __shfl_xor(s4.y,16);
  s4.z += __shfl_xor(s4.z,16); s4.w += __shfl_xor(s4.w,16);
  s4.x += __shfl_xor(s4.x,32); s4.y += __shfl_xor(s4.y,32);
  s4.z += __shfl_xor(s4.z,32); s4.w += __shfl_xor(s4.w,32);
  float acc = 0.f;
  #pragma unroll
  for (int l16 = 0; l16 < 16; ++l16){
    acc += __shfl(s4.x,l16) * W[(4*l16+0)*64 + lane];
    acc += __shfl(s4.y,l16) * W[(4*l16+1)*64 + lane];
    acc += __shfl(s4.z,l16) * W[(4*l16+2)*64 + lane];
    acc += __shfl(s4.w,l16) * W[(4*l16+3)*64 + lane];
  }
  float h = fmaxf(cdst[n]*acc + bg1[lane], 0.f) * csrc[n];
  hpre[(size_t)n*64 + lane] = h;
}

// ---- fused gather + dense2: score[n][c] = cdst[n]*(agg@Wg2)[c] + bg2[c] ----
__global__ __launch_bounds__(256) void fgd2(const float* __restrict__ hp,const int* __restrict__ rp,
                      const int* __restrict__ ss,const float* __restrict__ Wg2,
                      const float* __restrict__ bg2,const float* __restrict__ cdst,
                      float* __restrict__ score){
  __shared__ float W[64*16];
  for (int i = threadIdx.x; i < 64*16; i += 256) W[i] = Wg2[i];
  __syncthreads();
  int wave = threadIdx.x >> 6, lane = threadIdx.x & 63;
  int n = blockIdx.x*4 + wave;
  if (n >= NN) return;
  int q = lane >> 4, c0 = (lane & 15)*4;
  int beg = rp[n], end = rp[n+1];
  f32x4 s4 = {0.f,0.f,0.f,0.f};
  int e = beg + q;
  for (; e + 4 < end; e += 8){
    int i0 = ss[e], i1 = ss[e+4];
    f32x4 f0 = *(const f32x4*)(hp + (size_t)i0*64 + c0);
    f32x4 f1 = *(const f32x4*)(hp + (size_t)i1*64 + c0);
    s4 += f0 + f1;
  }
  if (e < end)
    s4 += *(const f32x4*)(hp + (size_t)ss[e]*64 + c0);
  s4.x += __shfl_xor(s4.x,16); s4.y += __shfl_xor(s4.y,16);
  s4.z += __shfl_xor(s4.z,16); s4.w += __shfl_xor(s4.w,16);
  s4.x += __shfl_xor(s4.x,32); s4.y += __shfl_xor(s4.y,32);
  s4.z += __shfl_xor(s4.z,32); s4.w += __shfl_xor(s4.w,32);
  int c = lane & 15;
  float acc = 0.f;
  #pragma unroll
  for (int l16 = 0; l16 < 16; ++l16){
    acc += __shfl(s4.x,l16) * W[(4*l16+0)*16 + c];
    acc += __shfl(s4.y,l16) * W[(4*l16+1)*16 + c];
    acc += __shfl(s4.z,l16) * W[(4*l16+2)*16 + c];
    acc += __shfl(s4.w,l16) * W[(4*l16+3)*16 + c];
  }
  if (lane < 16) score[(size_t)n*16 + lane] = cdst[n]*acc + bg2[lane];
}

extern "C" void kernel_launch(void* const* d_in, const int* in_sizes, int n_in,
                              void* d_out, int out_size, void* d_ws, size_t ws_size,
                              hipStream_t stream){
  const float* x   = (const float*)d_in[0];
  const int* src   = (const int*)d_in[1];
  const int* dst   = (const int*)d_in[2];
  const float* W1  = (const float*)d_in[3];
  const float* b1  = (const float*)d_in[4];
  const float* g1  = (const float*)d_in[5];
  const float* be1 = (const float*)d_in[6];
  const float* m1  = (const float*)d_in[7];
  const float* v1  = (const float*)d_in[8];
  const float* W2  = (const float*)d_in[9];
  const float* b2  = (const float*)d_in[10];
  const float* g2  = (const float*)d_in[11];
  const float* be2 = (const float*)d_in[12];
  const float* m2  = (const float*)d_in[13];
  const float* v2  = (const float*)d_in[14];
  const float* Wd  = (const float*)d_in[15];
  const float* bd  = (const float*)d_in[16];
  const float* Wg1 = (const float*)d_in[17];
  const float* bg1 = (const float*)d_in[18];
  const float* Wg2 = (const float*)d_in[19];
  const float* bg2 = (const float*)d_in[20];
  float* score = (float*)d_out;

  char* w = (char*)d_ws;
  size_t off = 0;
  auto alc = [&](size_t b){ size_t c = off; off += (b + 255) & ~(size_t)255; return c; };
  // keep the three zero-init arrays contiguous for a single memset
  size_t o_dout = alc((size_t)NN*4), o_din = alc((size_t)NN*4), o_cur = alc((size_t)NN*4);
  size_t zspan = off;                        // memset [0, zspan)
  size_t o_rp  = alc((size_t)(NN+1)*4), o_bsum = alc(256*4);
  size_t o_csrc = alc((size_t)NN*4), o_cdst = alc((size_t)NN*4);
  size_t o_T = alc((size_t)MM*H1*DECF*4), o_cbar = alc(DECF*4);
  size_t o_WB = alc((size_t)MM*DIN*DECF*2);
  size_t o_ss = alc((size_t)EE*4);
  size_t o_nf = alc((size_t)NN*64*4);
  size_t o_hp = alc((size_t)NN*64*4);

  int* dout = (int*)(w+o_dout); int* din = (int*)(w+o_din); int* cur = (int*)(w+o_cur);
  int* rp = (int*)(w+o_rp); int* bsum = (int*)(w+o_bsum);
  float* csrc = (float*)(w+o_csrc); float* cdst = (float*)(w+o_cdst);
  float* T = (float*)(w+o_T); float* cbar = (float*)(w+o_cbar);
  unsigned short* WBu = (unsigned short*)(w+o_WB);
  int* ss = (int*)(w+o_ss);
  float* nf = (float*)(w+o_nf); float* hp = (float*)(w+o_hp);

  hipMemsetAsync(w, 0, zspan, stream);

  prepA<<<(MM*H1*DECF)/256,256,0,stream>>>(W2,Wd,g2,v2,T);
  prepB<<<(MM*DIN*DECF)/256,256,0,stream>>>(W1,g1,v1,T,WBu);
  prepC<<<1,64,0,stream>>>(b1,g1,be1,m1,v1,b2,g2,be2,m2,v2,T,Wd,bd,cbar);

  degk<<<(EE+255)/256,256,0,stream>>>(src,dst,dout,din);
  int nb = (NN+1023)/1024;
  scan1<<<nb,1024,0,stream>>>(din,rp,bsum,NN);
  scan3n<<<(NN+255)/256,256,0,stream>>>(rp,bsum,dout,din,csrc,cdst);
  scatk<<<(EE+255)/256,256,0,stream>>>(src,dst,rp,cur,ss);

  gemm_nf<<<(NN+63)/64,256,0,stream>>>(x,(const short8v*)(w+o_WB),cbar,csrc,nf);

  fgd1<<<(NN+3)/4,256,0,stream>>>(nf,rp,ss,Wg1,bg1,csrc,cdst,hp);
  fgd2<<<(NN+3)/4,256,0,stream>>>(hp,rp,ss,Wg2,bg2,cdst,score);
}

// Round 3
// 797.415 us; speedup vs baseline: 1.0869x; 1.0756x over previous
//
#include <hip/hip_runtime.h>

#define NN 50000
#define EE 1600000
#define MM 2
#define DIN 2000
#define H1 500
#define LAT 128
#define DECF 64
#define KTOT (MM*DIN)        // 4000
#define KSTEPS (KTOT/32)     // 125
#define NTILES (NN/16)       // 3125 exact
#define EPSBN 1e-5f

typedef float f32x4 __attribute__((ext_vector_type(4)));
typedef short short8v __attribute__((ext_vector_type(8)));

__device__ __forceinline__ unsigned int pkbf(float a, float b){
  unsigned int ua = __float_as_uint(a), ub = __float_as_uint(b);
  ua = (ua + 0x7FFFu + ((ua>>16)&1u)) >> 16;
  ub = (ub + 0x7FFFu + ((ub>>16)&1u)) & 0xFFFF0000u;
  return ua | ub;
}

// ---- prepA: T[m][k][d] = sum_l W2[m][k][l]*a2[m][l]*Wd[m][l][d], a2 inline ----
__global__ __launch_bounds__(256) void prepA(const float* __restrict__ W2,const float* __restrict__ Wd,
                      const float* __restrict__ g2,const float* __restrict__ v2,
                      float* __restrict__ T){
  __shared__ float a2[LAT];
  int m = (blockIdx.x*4) / H1;              // 4 mk per block, never crosses m
  if (threadIdx.x < LAT)
    a2[threadIdx.x] = g2[m*LAT+threadIdx.x]*rsqrtf(v2[m*LAT+threadIdx.x]+EPSBN);
  __syncthreads();
  int g = blockIdx.x*256 + threadIdx.x;     // grid exact: 64000/256 = 250
  int d = g & 63; int mk = g >> 6; int k = mk % H1;
  const float* w2 = W2 + (size_t)(m*H1 + k)*LAT;
  const float* wd = Wd + (size_t)m*LAT*DECF + d;
  float acc = 0.f;
  for (int l = 0; l < LAT; ++l) acc += w2[l]*a2[l]*wd[(size_t)l*DECF];
  T[g] = acc;
}

// ---- prepB: Weff (bf16, B-fragment order), a1 inline ----
__global__ __launch_bounds__(256) void prepB(const float* __restrict__ W1,const float* __restrict__ g1,
                      const float* __restrict__ v1,const float* __restrict__ T,
                      unsigned short* __restrict__ WB){
  __shared__ float a1[H1];
  int m = (blockIdx.x*4) / DIN;             // 4 mi per block, never crosses m
  for (int k = threadIdx.x; k < H1; k += 256)
    a1[k] = g1[m*H1+k]*rsqrtf(v1[m*H1+k]+EPSBN);
  __syncthreads();
  int g = blockIdx.x*256 + threadIdx.x;     // grid exact: 256000/256 = 1000
  int d = g & 63; int mi = g >> 6; int i = mi % DIN;
  const float* w1 = W1 + (size_t)(m*DIN + i)*H1;
  const float* t  = T + (size_t)m*H1*DECF + d;
  float acc = 0.f;
  for (int k = 0; k < H1; ++k) acc += w1[k]*a1[k]*t[(size_t)k*DECF];
  acc *= 0.5f;
  unsigned int u = __float_as_uint(acc);
  unsigned short bf = (unsigned short)((u + 0x7FFFu + ((u>>16)&1u)) >> 16);
  int kc = m*DIN + i;
  int s = kc >> 5, kl = kc & 31;
  int laneB = ((kl>>3)<<4) | (d & 15);
  int t4 = d >> 4;
  WB[((size_t)((s*4 + t4)*64 + laneB))*8 + (kl & 7)] = bf;
}

// ---- prepC: cbar[d] = 0.5 * sum_m ( c1@T + c2@Wd + bd ), 128 threads, split halves ----
__global__ void prepC(const float* __restrict__ b1,const float* __restrict__ g1,const float* __restrict__ be1,
                      const float* __restrict__ m1,const float* __restrict__ v1,
                      const float* __restrict__ b2,const float* __restrict__ g2,const float* __restrict__ be2,
                      const float* __restrict__ m2,const float* __restrict__ v2,
                      const float* __restrict__ T,const float* __restrict__ Wd,
                      const float* __restrict__ bd, float* __restrict__ cbar){
  __shared__ float part[128];
  int d = threadIdx.x & 63, h = threadIdx.x >> 6;
  float s = 0.f;
  for (int m = 0; m < MM; ++m){
    if (h == 0) s += bd[m*DECF + d];
    const float* t = T + (size_t)m*H1*DECF + d;
    for (int k = h*(H1/2); k < (h+1)*(H1/2); ++k){
      float a = g1[m*H1+k]*rsqrtf(v1[m*H1+k]+EPSBN);
      float c = (b1[m*H1+k]-m1[m*H1+k])*a + be1[m*H1+k];
      s += c*t[(size_t)k*DECF];
    }
    const float* wd = Wd + (size_t)m*LAT*DECF + d;
    for (int l = h*(LAT/2); l < (h+1)*(LAT/2); ++l){
      float a = g2[m*LAT+l]*rsqrtf(v2[m*LAT+l]+EPSBN);
      float c = (b2[m*LAT+l]-m2[m*LAT+l])*a + be2[m*LAT+l];
      s += c*wd[(size_t)l*DECF];
    }
  }
  part[threadIdx.x] = s;
  __syncthreads();
  if (h == 0) cbar[d] = 0.5f*(part[d] + part[64+d]);
}

// ---- graph prep ----
__global__ void degk(const int* __restrict__ src,const int* __restrict__ dst,
                     int* __restrict__ dout,int* __restrict__ din){
  int e = blockIdx.x*blockDim.x + threadIdx.x;
  if (e >= EE) return;
  atomicAdd(&dout[src[e]], 1);
  atomicAdd(&din[dst[e]], 1);
}

__global__ __launch_bounds__(1024) void scan1(const int* __restrict__ deg, int* __restrict__ rp,
                      int* __restrict__ bsum, int n){
  __shared__ int sm[1024];
  int i = blockIdx.x*1024 + threadIdx.x;
  int v = (i < n) ? deg[i] : 0;
  sm[threadIdx.x] = v; __syncthreads();
  for (int off=1; off<1024; off<<=1){
    int t = (threadIdx.x >= off) ? sm[threadIdx.x-off] : 0;
    __syncthreads();
    sm[threadIdx.x] += t;
    __syncthreads();
  }
  if (i < n) rp[i] = sm[threadIdx.x] - v;
  if (threadIdx.x == 1023) bsum[blockIdx.x] = sm[1023];
}

// scan block-offset add + rp[NN] + degree-norm coefficients, fused
__global__ void scan3n(int* __restrict__ rp, const int* __restrict__ bsum,
                       const int* __restrict__ dout, const int* __restrict__ din,
                       float* __restrict__ csrc, float* __restrict__ cdst){
  int i = blockIdx.x*blockDim.x + threadIdx.x;
  if (i >= NN) return;
  int b = i >> 10;
  int base = 0;
  for (int j = 0; j < b; ++j) base += bsum[j];
  rp[i] += base;
  if (i == NN-1) rp[NN] = EE;               // total in-degree == E
  int a = dout[i]; if (a < 1) a = 1;
  int dd = din[i]; if (dd < 1) dd = 1;
  csrc[i] = rsqrtf((float)a);
  cdst[i] = rsqrtf((float)dd);
}

__global__ void scatk(const int* __restrict__ src,const int* __restrict__ dst,
                      const int* __restrict__ rp,int* __restrict__ cur,int* __restrict__ ss){
  int e = blockIdx.x*blockDim.x + threadIdx.x;
  if (e >= EE) return;
  int d = dst[e];
  int p = rp[d] + atomicAdd(&cur[d], 1);
  ss[p] = src[e];
}

// ---- main GEMM: nf[n][d] = (0.5*sum_m x_m[n,:]@Weff_m[:,d] + cbar[d]) * c_src[n] ----
// persistent blocks + dynamic wave-level 16-row tile assignment (load balance)
__global__ __launch_bounds__(256) void gemm_nf(
    const float* __restrict__ x, const short8v* __restrict__ WB,
    const float* __restrict__ cbar, const float* __restrict__ csrc,
    float* __restrict__ nfpre, int* __restrict__ ticket)
{
  const int lane = threadIdx.x & 63;
  const int r = lane & 15;
  const int kg = (lane >> 4) << 3;             // k-slot base: 0,8,16,24
  const int rg = (lane >> 4) << 2;             // D row group: 0,4,8,12
  const float cb0 = cbar[r], cb1 = cbar[16+r], cb2 = cbar[32+r], cb3 = cbar[48+r];

  while (true){
    int t = 0;
    if (lane == 0) t = atomicAdd(ticket, 1);
    t = __shfl(t, 0, 64);
    if (t >= NTILES) break;
    const int n0 = t*16;                       // rows n0..n0+15, always valid
    const float* xrow = x + (size_t)(n0 + r) * DIN;

    f32x4 acc0 = {0.f,0.f,0.f,0.f}, acc1 = acc0, acc2 = acc0, acc3 = acc0;
    f32x4 A0c, A1c; short8v B0c, B1c, B2c, B3c;
    {
      const float* p = xrow + kg;              // s=0 always in modality 0
      A0c = *(const f32x4*)p; A1c = *(const f32x4*)(p+4);
      const short8v* bp = WB + lane;
      B0c = bp[0]; B1c = bp[64]; B2c = bp[128]; B3c = bp[192];
    }
    for (int s = 0; s < KSTEPS-1; ++s){
      f32x4 A0n, A1n; short8v B0n, B1n, B2n, B3n;
      {
        int kr = (s+1)*32 + kg;
        const float* p = (kr < DIN) ? (xrow + kr)
                                    : (xrow + (size_t)(NN-1)*DIN + kr); // modality 1
        A0n = *(const f32x4*)p; A1n = *(const f32x4*)(p+4);
        const short8v* bp = WB + (size_t)(s+1)*256 + lane;
        B0n = bp[0]; B1n = bp[64]; B2n = bp[128]; B3n = bp[192];
      }
      union { short8v v; unsigned int u[4]; } AF;
      AF.u[0]=pkbf(A0c[0],A0c[1]); AF.u[1]=pkbf(A0c[2],A0c[3]);
      AF.u[2]=pkbf(A1c[0],A1c[1]); AF.u[3]=pkbf(A1c[2],A1c[3]);
      acc0 = __builtin_amdgcn_mfma_f32_16x16x32_bf16(AF.v, B0c, acc0, 0,0,0);
      acc1 = __builtin_amdgcn_mfma_f32_16x16x32_bf16(AF.v, B1c, acc1, 0,0,0);
      acc2 = __builtin_amdgcn_mfma_f32_16x16x32_bf16(AF.v, B2c, acc2, 0,0,0);
      acc3 = __builtin_amdgcn_mfma_f32_16x16x32_bf16(AF.v, B3c, acc3, 0,0,0);
      A0c=A0n; A1c=A1n; B0c=B0n; B1c=B1n; B2c=B2n; B3c=B3n;
    }
    {
      union { short8v v; unsigned int u[4]; } AF;
      AF.u[0]=pkbf(A0c[0],A0c[1]); AF.u[1]=pkbf(A0c[2],A0c[3]);
      AF.u[2]=pkbf(A1c[0],A1c[1]); AF.u[3]=pkbf(A1c[2],A1c[3]);
      acc0 = __builtin_amdgcn_mfma_f32_16x16x32_bf16(AF.v, B0c, acc0, 0,0,0);
      acc1 = __builtin_amdgcn_mfma_f32_16x16x32_bf16(AF.v, B1c, acc1, 0,0,0);
      acc2 = __builtin_amdgcn_mfma_f32_16x16x32_bf16(AF.v, B2c, acc2, 0,0,0);
      acc3 = __builtin_amdgcn_mfma_f32_16x16x32_bf16(AF.v, B3c, acc3, 0,0,0);
    }
    #pragma unroll
    for (int rr = 0; rr < 4; ++rr){
      int rowD = n0 + rg + rr;
      float cs = csrc[rowD];
      float* o = nfpre + (size_t)rowD*64 + r;
      o[0]  = (acc0[rr] + cb0)*cs;
      o[16] = (acc1[rr] + cb1)*cs;
      o[32] = (acc2[rr] + cb2)*cs;
      o[48] = (acc3[rr] + cb3)*cs;
    }
  }
}

// ---- fused gather + dense1: hpre[n][j] = relu(cdst[n]*(agg@Wg1)[j]+bg1[j])*csrc[n] ----
__global__ __launch_bounds__(512) void fgd1(const float* __restrict__ nf,const int* __restrict__ rp,
                      const int* __restrict__ ss,const float* __restrict__ Wg1,
                      const float* __restrict__ bg1,const float* __restrict__ csrc,
                      const float* __restrict__ cdst,float* __restrict__ hpre){
  __shared__ float W[64*64];
  for (int i = threadIdx.x; i < 64*64; i += 512) W[i] = Wg1[i];
  __syncthreads();
  int wave = threadIdx.x >> 6, lane = threadIdx.x & 63;
  int n = blockIdx.x*8 + wave;                 // grid exact: 50000/8 = 6250
  int q = lane >> 4, c0 = (lane & 15)*4;
  int beg = rp[n], end = rp[n+1];
  f32x4 s4 = {0.f,0.f,0.f,0.f};
  int e = beg + q;
  for (; e + 12 < end; e += 16){               // 4 rows in flight per lane
    int i0 = ss[e], i1 = ss[e+4], i2 = ss[e+8], i3 = ss[e+12];
    f32x4 f0 = *(const f32x4*)(nf + (size_t)i0*64 + c0);
    f32x4 f1 = *(const f32x4*)(nf + (size_t)i1*64 + c0);
    f32x4 f2 = *(const f32x4*)(nf + (size_t)i2*64 + c0);
    f32x4 f3 = *(const f32x4*)(nf + (size_t)i3*64 + c0);
    s4 += (f0 + f1) + (f2 + f3);
  }
  for (; e < end; e += 4)
    s4 += *(const f32x4*)(nf + (size_t)ss[e]*64 + c0);
  // reduce across the 4 q-groups
  s4.x += __shfl_xor(s4.x,16); s4.y += __shfl_xor(s4.y,16);
  s4.z += __shfl_xor(s4.z,16); s4.w += __shfl_xor(s4.w,16);
  s4.x += __shfl_xor(s4.x,32); s4.y += __shfl_xor(s4.y,32);
  s4.z += __shfl_xor(s4.z,32); s4.w += __shfl_xor(s4.w,32);
  float acc = 0.f;
  #pragma unroll
  for (int l16 = 0; l16 < 16; ++l16){
    acc += __shfl(s4.x,l16) * W[(4*l16+0)*64 + lane];
    acc += __shfl(s4.y,l16) * W[(4*l16+1)*64 + lane];
    acc += __shfl(s4.z,l16) * W[(4*l16+2)*64 + lane];
    acc += __shfl(s4.w,l16) * W[(4*l16+3)*64 + lane];
  }
  float h = fmaxf(cdst[n]*acc + bg1[lane], 0.f) * csrc[n];
  hpre[(size_t)n*64 + lane] = h;
}

// ---- fused gather + dense2: score[n][c] = cdst[n]*(agg@Wg2)[c] + bg2[c] ----
__global__ __launch_bounds__(512) void fgd2(const float* __restrict__ hp,const int* __restrict__ rp,
                      const int* __restrict__ ss,const float* __restrict__ Wg2,
                      const float* __restrict__ bg2,const float* __restrict__ cdst,
                      float* __restrict__ score){
  __shared__ float W[64*16];
  for (int i = threadIdx.x; i < 64*16; i += 512) W[i] = Wg2[i];
  __syncthreads();
  int wave = threadIdx.x >> 6, lane = threadIdx.x & 63;
  int n = blockIdx.x*8 + wave;
  int q = lane >> 4, c0 = (lane & 15)*4;
  int beg = rp[n], end = rp[n+1];
  f32x4 s4 = {0.f,0.f,0.f,0.f};
  int e = beg + q;
  for (; e + 12 < end; e += 16){
    int i0 = ss[e], i1 = ss[e+4], i2 = ss[e+8], i3 = ss[e+12];
    f32x4 f0 = *(const f32x4*)(hp + (size_t)i0*64 + c0);
    f32x4 f1 = *(const f32x4*)(hp + (size_t)i1*64 + c0);
    f32x4 f2 = *(const f32x4*)(hp + (size_t)i2*64 + c0);
    f32x4 f3 = *(const f32x4*)(hp + (size_t)i3*64 + c0);
    s4 += (f0 + f1) + (f2 + f3);
  }
  for (; e < end; e += 4)
    s4 += *(const f32x4*)(hp + (size_t)ss[e]*64 + c0);
  s4.x += __shfl_xor(s4.x,16); s4.y += __shfl_xor(s4.y,16);
  s4.z += __shfl_xor(s4.z,16); s4.w += __shfl_xor(s4.w,16);
  s4.x += __shfl_xor(s4.x,32); s4.y += __shfl_xor(s4.y,32);
  s4.z += __shfl_xor(s4.z,32); s4.w += __shfl_xor(s4.w,32);
  int c = lane & 15;
  float acc = 0.f;
  #pragma unroll
  for (int l16 = 0; l16 < 16; ++l16){
    acc += __shfl(s4.x,l16) * W[(4*l16+0)*16 + c];
    acc += __shfl(s4.y,l16) * W[(4*l16+1)*16 + c];
    acc += __shfl(s4.z,l16) * W[(4*l16+2)*16 + c];
    acc += __shfl(s4.w,l16) * W[(4*l16+3)*16 + c];
  }
  if (lane < 16) score[(size_t)n*16 + lane] = cdst[n]*acc + bg2[lane];
}

extern "C" void kernel_launch(void* const* d_in, const int* in_sizes, int n_in,
                              void* d_out, int out_size, void* d_ws, size_t ws_size,
                              hipStream_t stream){
  const float* x   = (const float*)d_in[0];
  const int* src   = (const int*)d_in[1];
  const int* dst   = (const int*)d_in[2];
  const float* W1  = (const float*)d_in[3];
  const float* b1  = (const float*)d_in[4];
  const float* g1  = (const float*)d_in[5];
  const float* be1 = (const float*)d_in[6];
  const float* m1  = (const float*)d_in[7];
  const float* v1  = (const float*)d_in[8];
  const float* W2  = (const float*)d_in[9];
  const float* b2  = (const float*)d_in[10];
  const float* g2  = (const float*)d_in[11];
  const float* be2 = (const float*)d_in[12];
  const float* m2  = (const float*)d_in[13];
  const float* v2  = (const float*)d_in[14];
  const float* Wd  = (const float*)d_in[15];
  const float* bd  = (const float*)d_in[16];
  const float* Wg1 = (const float*)d_in[17];
  const float* bg1 = (const float*)d_in[18];
  const float* Wg2 = (const float*)d_in[19];
  const float* bg2 = (const float*)d_in[20];
  float* score = (float*)d_out;

  char* w = (char*)d_ws;
  size_t off = 0;
  auto alc = [&](size_t b){ size_t c = off; off += (b + 255) & ~(size_t)255; return c; };
  // zero-init region: dout, din, cur, ticket (single memset)
  size_t o_dout = alc((size_t)NN*4), o_din = alc((size_t)NN*4), o_cur = alc((size_t)NN*4);
  size_t o_tick = alc(256);
  size_t zspan = off;                        // memset [0, zspan)
  size_t o_rp  = alc((size_t)(NN+1)*4), o_bsum = alc(256*4);
  size_t o_csrc = alc((size_t)NN*4), o_cdst = alc((size_t)NN*4);
  size_t o_T = alc((size_t)MM*H1*DECF*4), o_cbar = alc(DECF*4);
  size_t o_WB = alc((size_t)MM*DIN*DECF*2);
  size_t o_ss = alc((size_t)EE*4);
  size_t o_nf = alc((size_t)NN*64*4);
  size_t o_hp = alc((size_t)NN*64*4);

  int* dout = (int*)(w+o_dout); int* din = (int*)(w+o_din); int* cur = (int*)(w+o_cur);
  int* tick = (int*)(w+o_tick);
  int* rp = (int*)(w+o_rp); int* bsum = (int*)(w+o_bsum);
  float* csrc = (float*)(w+o_csrc); float* cdst = (float*)(w+o_cdst);
  float* T = (float*)(w+o_T); float* cbar = (float*)(w+o_cbar);
  unsigned short* WBu = (unsigned short*)(w+o_WB);
  int* ss = (int*)(w+o_ss);
  float* nf = (float*)(w+o_nf); float* hp = (float*)(w+o_hp);

  hipMemsetAsync(w, 0, zspan, stream);

  prepA<<<(MM*H1*DECF)/256,256,0,stream>>>(W2,Wd,g2,v2,T);
  prepB<<<(MM*DIN*DECF)/256,256,0,stream>>>(W1,g1,v1,T,WBu);
  prepC<<<1,128,0,stream>>>(b1,g1,be1,m1,v1,b2,g2,be2,m2,v2,T,Wd,bd,cbar);

  degk<<<(EE+255)/256,256,0,stream>>>(src,dst,dout,din);
  int nb = (NN+1023)/1024;
  scan1<<<nb,1024,0,stream>>>(din,rp,bsum,NN);
  scan3n<<<(NN+255)/256,256,0,stream>>>(rp,bsum,dout,din,csrc,cdst);
  scatk<<<(EE+255)/256,256,0,stream>>>(src,dst,rp,cur,ss);

  gemm_nf<<<768,256,0,stream>>>(x,(const short8v*)(w+o_WB),cbar,csrc,nf,tick);

  fgd1<<<NN/8,512,0,stream>>>(nf,rp,ss,Wg1,bg1,csrc,cdst,hp);
  fgd2<<<NN/8,512,0,stream>>>(hp,rp,ss,Wg2,bg2,cdst,score);
}

// Round 4
// 702.700 us; speedup vs baseline: 1.2334x; 1.1348x over previous
//
#include <hip/hip_runtime.h>

#define NN 50000
#define EE 1600000
#define MM 2
#define DIN 2000
#define H1 500
#define LAT 128
#define DECF 64
#define KTOT (MM*DIN)        // 4000
#define KSTEPS (KTOT/32)     // 125
#define NTILES (NN/16)       // 3125 exact
#define GEMM_BLKS 768
#define DEG_BLKS 256
#define EPSBN 1e-5f

typedef float f32x4 __attribute__((ext_vector_type(4)));
typedef short short8v __attribute__((ext_vector_type(8)));
typedef unsigned int u32x2 __attribute__((ext_vector_type(2)));

__device__ __forceinline__ unsigned int pkbf(float a, float b){
  unsigned int ua = __float_as_uint(a), ub = __float_as_uint(b);
  ua = (ua + 0x7FFFu + ((ua>>16)&1u)) >> 16;
  ub = (ub + 0x7FFFu + ((ub>>16)&1u)) & 0xFFFF0000u;
  return ua | ub;
}
__device__ __forceinline__ unsigned short pk1(float a){
  unsigned int u = __float_as_uint(a);
  return (unsigned short)((u + 0x7FFFu + ((u>>16)&1u)) >> 16);
}
__device__ __forceinline__ float bfe0(unsigned int w){ return __uint_as_float(w<<16); }
__device__ __forceinline__ float bfe1(unsigned int w){ return __uint_as_float(w & 0xFFFF0000u); }

// ---- prepA: T[m][k][d] = sum_l W2[m][k][l]*a2[m][l]*Wd[m][l][d], a2 inline ----
__global__ __launch_bounds__(256) void prepA(const float* __restrict__ W2,const float* __restrict__ Wd,
                      const float* __restrict__ g2,const float* __restrict__ v2,
                      float* __restrict__ T){
  __shared__ float a2[LAT];
  int m = (blockIdx.x*4) / H1;
  if (threadIdx.x < LAT)
    a2[threadIdx.x] = g2[m*LAT+threadIdx.x]*rsqrtf(v2[m*LAT+threadIdx.x]+EPSBN);
  __syncthreads();
  int g = blockIdx.x*256 + threadIdx.x;     // grid exact: 64000/256 = 250
  int d = g & 63; int mk = g >> 6; int k = mk % H1;
  const float* w2 = W2 + (size_t)(m*H1 + k)*LAT;
  const float* wd = Wd + (size_t)m*LAT*DECF + d;
  float acc = 0.f;
  for (int l = 0; l < LAT; ++l) acc += w2[l]*a2[l]*wd[(size_t)l*DECF];
  T[g] = acc;
}

// ---- prepB: Weff (bf16, B-fragment order), a1 inline ----
__global__ __launch_bounds__(256) void prepB(const float* __restrict__ W1,const float* __restrict__ g1,
                      const float* __restrict__ v1,const float* __restrict__ T,
                      unsigned short* __restrict__ WB){
  __shared__ float a1[H1];
  int m = (blockIdx.x*4) / DIN;
  for (int k = threadIdx.x; k < H1; k += 256)
    a1[k] = g1[m*H1+k]*rsqrtf(v1[m*H1+k]+EPSBN);
  __syncthreads();
  int g = blockIdx.x*256 + threadIdx.x;     // grid exact: 256000/256 = 1000
  int d = g & 63; int mi = g >> 6; int i = mi % DIN;
  const float* w1 = W1 + (size_t)(m*DIN + i)*H1;
  const float* t  = T + (size_t)m*H1*DECF + d;
  float acc = 0.f;
  for (int k = 0; k < H1; ++k) acc += w1[k]*a1[k]*t[(size_t)k*DECF];
  acc *= 0.5f;
  unsigned int u = __float_as_uint(acc);
  unsigned short bf = (unsigned short)((u + 0x7FFFu + ((u>>16)&1u)) >> 16);
  int kc = m*DIN + i;
  int s = kc >> 5, kl = kc & 31;
  int laneB = ((kl>>3)<<4) | (d & 15);
  int t4 = d >> 4;
  WB[((size_t)((s*4 + t4)*64 + laneB))*8 + (kl & 7)] = bf;
}

// ---- prepC: cbar[d] = 0.5 * sum_m ( c1@T + c2@Wd + bd ) ----
__global__ void prepC(const float* __restrict__ b1,const float* __restrict__ g1,const float* __restrict__ be1,
                      const float* __restrict__ m1,const float* __restrict__ v1,
                      const float* __restrict__ b2,const float* __restrict__ g2,const float* __restrict__ be2,
                      const float* __restrict__ m2,const float* __restrict__ v2,
                      const float* __restrict__ T,const float* __restrict__ Wd,
                      const float* __restrict__ bd, float* __restrict__ cbar){
  __shared__ float part[128];
  int d = threadIdx.x & 63, h = threadIdx.x >> 6;
  float s = 0.f;
  for (int m = 0; m < MM; ++m){
    if (h == 0) s += bd[m*DECF + d];
    const float* t = T + (size_t)m*H1*DECF + d;
    for (int k = h*(H1/2); k < (h+1)*(H1/2); ++k){
      float a = g1[m*H1+k]*rsqrtf(v1[m*H1+k]+EPSBN);
      float c = (b1[m*H1+k]-m1[m*H1+k])*a + be1[m*H1+k];
      s += c*t[(size_t)k*DECF];
    }
    const float* wd = Wd + (size_t)m*LAT*DECF + d;
    for (int l = h*(LAT/2); l < (h+1)*(LAT/2); ++l){
      float a = g2[m*LAT+l]*rsqrtf(v2[m*LAT+l]+EPSBN);
      float c = (b2[m*LAT+l]-m2[m*LAT+l])*a + be2[m*LAT+l];
      s += c*wd[(size_t)l*DECF];
    }
  }
  part[threadIdx.x] = s;
  __syncthreads();
  if (h == 0) cbar[d] = 0.5f*(part[d] + part[64+d]);
}

__global__ __launch_bounds__(1024) void scan1(const int* __restrict__ deg, int* __restrict__ rp,
                      int* __restrict__ bsum, int n){
  __shared__ int sm[1024];
  int i = blockIdx.x*1024 + threadIdx.x;
  int v = (i < n) ? deg[i] : 0;
  sm[threadIdx.x] = v; __syncthreads();
  for (int off=1; off<1024; off<<=1){
    int t = (threadIdx.x >= off) ? sm[threadIdx.x-off] : 0;
    __syncthreads();
    sm[threadIdx.x] += t;
    __syncthreads();
  }
  if (i < n) rp[i] = sm[threadIdx.x] - v;
  if (threadIdx.x == 1023) bsum[blockIdx.x] = sm[1023];
}

__global__ void scan3n(int* __restrict__ rp, const int* __restrict__ bsum,
                       const int* __restrict__ dout, const int* __restrict__ din,
                       float* __restrict__ csrc, float* __restrict__ cdst){
  int i = blockIdx.x*blockDim.x + threadIdx.x;
  if (i >= NN) return;
  int b = i >> 10;
  int base = 0;
  for (int j = 0; j < b; ++j) base += bsum[j];
  rp[i] += base;
  if (i == NN-1) rp[NN] = EE;
  int a = dout[i]; if (a < 1) a = 1;
  int dd = din[i]; if (dd < 1) dd = 1;
  csrc[i] = rsqrtf((float)a);
  cdst[i] = rsqrtf((float)dd);
}

__global__ void scatk(const int* __restrict__ src,const int* __restrict__ dst,
                      const int* __restrict__ rp,int* __restrict__ cur,int* __restrict__ ss){
  int e = blockIdx.x*blockDim.x + threadIdx.x;
  if (e >= EE) return;
  int d = dst[e];
  int p = rp[d] + atomicAdd(&cur[d], 1);
  ss[p] = src[e];
}

// ---- fused GEMM (768 ticket blocks) + degree histogram (256 blocks) ----
// nf_raw[n][d] = bf16( 0.5*sum_m x_m[n,:]@Weff_m[:,d] + cbar[d] )   (csrc applied in fgd1)
__global__ __launch_bounds__(256,4) void gemm_deg(
    const float* __restrict__ x, const short8v* __restrict__ WB,
    const float* __restrict__ cbar,
    unsigned short* __restrict__ nfb, int* __restrict__ ticket,
    const int* __restrict__ src, const int* __restrict__ dst,
    int* __restrict__ dout, int* __restrict__ din)
{
  if (blockIdx.x >= GEMM_BLKS){
    int t0 = (blockIdx.x - GEMM_BLKS)*256 + threadIdx.x;
    for (int e = t0; e < EE; e += 256*DEG_BLKS){
      atomicAdd(&dout[src[e]], 1);
      atomicAdd(&din[dst[e]], 1);
    }
    return;
  }
  const int lane = threadIdx.x & 63;
  const int r = lane & 15;
  const int kg = (lane >> 4) << 3;             // k-slot base: 0,8,16,24
  const int rg = (lane >> 4) << 2;             // D row group: 0,4,8,12
  const float cb0 = cbar[r], cb1 = cbar[16+r], cb2 = cbar[32+r], cb3 = cbar[48+r];

  while (true){
    int t = 0;
    if (lane == 0) t = atomicAdd(ticket, 1);
    t = __shfl(t, 0, 64);
    if (t >= NTILES) break;
    const int n0 = t*16;
    const float* xrow = x + (size_t)(n0 + r) * DIN;

    f32x4 acc0 = {0.f,0.f,0.f,0.f}, acc1 = acc0, acc2 = acc0, acc3 = acc0;
    f32x4 A0c, A1c; short8v B0c, B1c, B2c, B3c;
    {
      const float* p = xrow + kg;
      A0c = *(const f32x4*)p; A1c = *(const f32x4*)(p+4);
      const short8v* bp = WB + lane;
      B0c = bp[0]; B1c = bp[64]; B2c = bp[128]; B3c = bp[192];
    }
    for (int s = 0; s < KSTEPS-1; ++s){
      f32x4 A0n, A1n; short8v B0n, B1n, B2n, B3n;
      {
        int kr = (s+1)*32 + kg;
        const float* p = (kr < DIN) ? (xrow + kr)
                                    : (xrow + (size_t)(NN-1)*DIN + kr); // modality 1
        A0n = *(const f32x4*)p; A1n = *(const f32x4*)(p+4);
        const short8v* bp = WB + (size_t)(s+1)*256 + lane;
        B0n = bp[0]; B1n = bp[64]; B2n = bp[128]; B3n = bp[192];
      }
      union { short8v v; unsigned int u[4]; } AF;
      AF.u[0]=pkbf(A0c[0],A0c[1]); AF.u[1]=pkbf(A0c[2],A0c[3]);
      AF.u[2]=pkbf(A1c[0],A1c[1]); AF.u[3]=pkbf(A1c[2],A1c[3]);
      acc0 = __builtin_amdgcn_mfma_f32_16x16x32_bf16(AF.v, B0c, acc0, 0,0,0);
      acc1 = __builtin_amdgcn_mfma_f32_16x16x32_bf16(AF.v, B1c, acc1, 0,0,0);
      acc2 = __builtin_amdgcn_mfma_f32_16x16x32_bf16(AF.v, B2c, acc2, 0,0,0);
      acc3 = __builtin_amdgcn_mfma_f32_16x16x32_bf16(AF.v, B3c, acc3, 0,0,0);
      A0c=A0n; A1c=A1n; B0c=B0n; B1c=B1n; B2c=B2n; B3c=B3n;
    }
    {
      union { short8v v; unsigned int u[4]; } AF;
      AF.u[0]=pkbf(A0c[0],A0c[1]); AF.u[1]=pkbf(A0c[2],A0c[3]);
      AF.u[2]=pkbf(A1c[0],A1c[1]); AF.u[3]=pkbf(A1c[2],A1c[3]);
      acc0 = __builtin_amdgcn_mfma_f32_16x16x32_bf16(AF.v, B0c, acc0, 0,0,0);
      acc1 = __builtin_amdgcn_mfma_f32_16x16x32_bf16(AF.v, B1c, acc1, 0,0,0);
      acc2 = __builtin_amdgcn_mfma_f32_16x16x32_bf16(AF.v, B2c, acc2, 0,0,0);
      acc3 = __builtin_amdgcn_mfma_f32_16x16x32_bf16(AF.v, B3c, acc3, 0,0,0);
    }
    #pragma unroll
    for (int rr = 0; rr < 4; ++rr){
      int rowD = n0 + rg + rr;
      unsigned short* o = nfb + (size_t)rowD*64 + r;
      o[0]  = pk1(acc0[rr] + cb0);
      o[16] = pk1(acc1[rr] + cb1);
      o[32] = pk1(acc2[rr] + cb2);
      o[48] = pk1(acc3[rr] + cb3);
    }
  }
}

// ---- fused gather(csrc-scaled, bf16) + dense1 -> hp (bf16) ----
// hp[n][j] = bf16( relu(cdst[n]*(sum_e csrc[src_e]*nf[src_e])@Wg1[j] + bg1[j]) * csrc[n] )
__global__ __launch_bounds__(512,4) void fgd1(const unsigned short* __restrict__ nfb,
                      const int* __restrict__ rp,const int* __restrict__ ss,
                      const float* __restrict__ Wg1,const float* __restrict__ bg1,
                      const float* __restrict__ csrc,const float* __restrict__ cdst,
                      unsigned short* __restrict__ hpb){
  __shared__ float W[64*64];
  for (int i = threadIdx.x; i < 64*64; i += 512) W[i] = Wg1[i];
  __syncthreads();
  int wave = threadIdx.x >> 6, lane = threadIdx.x & 63;
  int q = lane >> 4, cc = (lane & 15)*4;       // 4 ushorts (8B) per lane
  const int NW = 512*8;                        // total waves
  for (int n = blockIdx.x*8 + wave; n < NN; n += NW){
    int beg = rp[n], end = rp[n+1];
    f32x4 s4 = {0.f,0.f,0.f,0.f};
    int e = beg + q;
    for (; e + 12 < end; e += 16){
      int i0 = ss[e], i1 = ss[e+4], i2 = ss[e+8], i3 = ss[e+12];
      float c0 = csrc[i0], c1 = csrc[i1], c2 = csrc[i2], c3 = csrc[i3];
      u32x2 w0 = *(const u32x2*)(nfb + (size_t)i0*64 + cc);
      u32x2 w1 = *(const u32x2*)(nfb + (size_t)i1*64 + cc);
      u32x2 w2 = *(const u32x2*)(nfb + (size_t)i2*64 + cc);
      u32x2 w3 = *(const u32x2*)(nfb + (size_t)i3*64 + cc);
      s4.x += c0*bfe0(w0.x) + c1*bfe0(w1.x) + c2*bfe0(w2.x) + c3*bfe0(w3.x);
      s4.y += c0*bfe1(w0.x) + c1*bfe1(w1.x) + c2*bfe1(w2.x) + c3*bfe1(w3.x);
      s4.z += c0*bfe0(w0.y) + c1*bfe0(w1.y) + c2*bfe0(w2.y) + c3*bfe0(w3.y);
      s4.w += c0*bfe1(w0.y) + c1*bfe1(w1.y) + c2*bfe1(w2.y) + c3*bfe1(w3.y);
    }
    for (; e < end; e += 4){
      int i0 = ss[e]; float c0 = csrc[i0];
      u32x2 w0 = *(const u32x2*)(nfb + (size_t)i0*64 + cc);
      s4.x += c0*bfe0(w0.x); s4.y += c0*bfe1(w0.x);
      s4.z += c0*bfe0(w0.y); s4.w += c0*bfe1(w0.y);
    }
    s4.x += __shfl_xor(s4.x,16); s4.y += __shfl_xor(s4.y,16);
    s4.z += __shfl_xor(s4.z,16); s4.w += __shfl_xor(s4.w,16);
    s4.x += __shfl_xor(s4.x,32); s4.y += __shfl_xor(s4.y,32);
    s4.z += __shfl_xor(s4.z,32); s4.w += __shfl_xor(s4.w,32);
    float acc = 0.f;
    #pragma unroll
    for (int l16 = 0; l16 < 16; ++l16){
      acc += __shfl(s4.x,l16) * W[(4*l16+0)*64 + lane];
      acc += __shfl(s4.y,l16) * W[(4*l16+1)*64 + lane];
      acc += __shfl(s4.z,l16) * W[(4*l16+2)*64 + lane];
      acc += __shfl(s4.w,l16) * W[(4*l16+3)*64 + lane];
    }
    float h = fmaxf(cdst[n]*acc + bg1[lane], 0.f) * csrc[n];
    hpb[(size_t)n*64 + lane] = pk1(h);
  }
}

// ---- fused gather(bf16, pre-scaled hp) + dense2 -> score (fp32) ----
__global__ __launch_bounds__(512,4) void fgd2(const unsigned short* __restrict__ hpb,
                      const int* __restrict__ rp,const int* __restrict__ ss,
                      const float* __restrict__ Wg2,const float* __restrict__ bg2,
                      const float* __restrict__ cdst,float* __restrict__ score){
  __shared__ float W[64*16];
  for (int i = threadIdx.x; i < 64*16; i += 512) W[i] = Wg2[i];
  __syncthreads();
  int wave = threadIdx.x >> 6, lane = threadIdx.x & 63;
  int q = lane >> 4, cc = (lane & 15)*4;
  const int NW = 512*8;
  for (int n = blockIdx.x*8 + wave; n < NN; n += NW){
    int beg = rp[n], end = rp[n+1];
    f32x4 s4 = {0.f,0.f,0.f,0.f};
    int e = beg + q;
    for (; e + 12 < end; e += 16){
      int i0 = ss[e], i1 = ss[e+4], i2 = ss[e+8], i3 = ss[e+12];
      u32x2 w0 = *(const u32x2*)(hpb + (size_t)i0*64 + cc);
      u32x2 w1 = *(const u32x2*)(hpb + (size_t)i1*64 + cc);
      u32x2 w2 = *(const u32x2*)(hpb + (size_t)i2*64 + cc);
      u32x2 w3 = *(const u32x2*)(hpb + (size_t)i3*64 + cc);
      s4.x += bfe0(w0.x) + bfe0(w1.x) + bfe0(w2.x) + bfe0(w3.x);
      s4.y += bfe1(w0.x) + bfe1(w1.x) + bfe1(w2.x) + bfe1(w3.x);
      s4.z += bfe0(w0.y) + bfe0(w1.y) + bfe0(w2.y) + bfe0(w3.y);
      s4.w += bfe1(w0.y) + bfe1(w1.y) + bfe1(w2.y) + bfe1(w3.y);
    }
    for (; e < end; e += 4){
      u32x2 w0 = *(const u32x2*)(hpb + (size_t)ss[e]*64 + cc);
      s4.x += bfe0(w0.x); s4.y += bfe1(w0.x);
      s4.z += bfe0(w0.y); s4.w += bfe1(w0.y);
    }
    s4.x += __shfl_xor(s4.x,16); s4.y += __shfl_xor(s4.y,16);
    s4.z += __shfl_xor(s4.z,16); s4.w += __shfl_xor(s4.w,16);
    s4.x += __shfl_xor(s4.x,32); s4.y += __shfl_xor(s4.y,32);
    s4.z += __shfl_xor(s4.z,32); s4.w += __shfl_xor(s4.w,32);
    int c = lane & 15;
    float acc = 0.f;
    #pragma unroll
    for (int l16 = 0; l16 < 16; ++l16){
      acc += __shfl(s4.x,l16) * W[(4*l16+0)*16 + c];
      acc += __shfl(s4.y,l16) * W[(4*l16+1)*16 + c];
      acc += __shfl(s4.z,l16) * W[(4*l16+2)*16 + c];
      acc += __shfl(s4.w,l16) * W[(4*l16+3)*16 + c];
    }
    if (lane < 16) score[(size_t)n*16 + lane] = cdst[n]*acc + bg2[lane];
  }
}

extern "C" void kernel_launch(void* const* d_in, const int* in_sizes, int n_in,
                              void* d_out, int out_size, void* d_ws, size_t ws_size,
                              hipStream_t stream){
  const float* x   = (const float*)d_in[0];
  const int* src   = (const int*)d_in[1];
  const int* dst   = (const int*)d_in[2];
  const float* W1  = (const float*)d_in[3];
  const float* b1  = (const float*)d_in[4];
  const float* g1  = (const float*)d_in[5];
  const float* be1 = (const float*)d_in[6];
  const float* m1  = (const float*)d_in[7];
  const float* v1  = (const float*)d_in[8];
  const float* W2  = (const float*)d_in[9];
  const float* b2  = (const float*)d_in[10];
  const float* g2  = (const float*)d_in[11];
  const float* be2 = (const float*)d_in[12];
  const float* m2  = (const float*)d_in[13];
  const float* v2  = (const float*)d_in[14];
  const float* Wd  = (const float*)d_in[15];
  const float* bd  = (const float*)d_in[16];
  const float* Wg1 = (const float*)d_in[17];
  const float* bg1 = (const float*)d_in[18];
  const float* Wg2 = (const float*)d_in[19];
  const float* bg2 = (const float*)d_in[20];
  float* score = (float*)d_out;

  char* w = (char*)d_ws;
  size_t off = 0;
  auto alc = [&](size_t b){ size_t c = off; off += (b + 255) & ~(size_t)255; return c; };
  // zero-init region: dout, din, cur, ticket (single memset)
  size_t o_dout = alc((size_t)NN*4), o_din = alc((size_t)NN*4), o_cur = alc((size_t)NN*4);
  size_t o_tick = alc(256);
  size_t zspan = off;
  size_t o_rp  = alc((size_t)(NN+1)*4), o_bsum = alc(256*4);
  size_t o_csrc = alc((size_t)NN*4), o_cdst = alc((size_t)NN*4);
  size_t o_T = alc((size_t)MM*H1*DECF*4), o_cbar = alc(DECF*4);
  size_t o_WB = alc((size_t)MM*DIN*DECF*2);
  size_t o_ss = alc((size_t)EE*4);
  size_t o_nf = alc((size_t)NN*64*2);   // bf16
  size_t o_hp = alc((size_t)NN*64*2);   // bf16

  int* dout = (int*)(w+o_dout); int* din = (int*)(w+o_din); int* cur = (int*)(w+o_cur);
  int* tick = (int*)(w+o_tick);
  int* rp = (int*)(w+o_rp); int* bsum = (int*)(w+o_bsum);
  float* csrc = (float*)(w+o_csrc); float* cdst = (float*)(w+o_cdst);
  float* T = (float*)(w+o_T); float* cbar = (float*)(w+o_cbar);
  unsigned short* WBu = (unsigned short*)(w+o_WB);
  int* ss = (int*)(w+o_ss);
  unsigned short* nfb = (unsigned short*)(w+o_nf);
  unsigned short* hpb = (unsigned short*)(w+o_hp);

  hipMemsetAsync(w, 0, zspan, stream);

  prepA<<<(MM*H1*DECF)/256,256,0,stream>>>(W2,Wd,g2,v2,T);
  prepB<<<(MM*DIN*DECF)/256,256,0,stream>>>(W1,g1,v1,T,WBu);
  prepC<<<1,128,0,stream>>>(b1,g1,be1,m1,v1,b2,g2,be2,m2,v2,T,Wd,bd,cbar);

  gemm_deg<<<GEMM_BLKS+DEG_BLKS,256,0,stream>>>(x,(const short8v*)(w+o_WB),cbar,
                                                nfb,tick,src,dst,dout,din);

  int nb = (NN+1023)/1024;
  scan1<<<nb,1024,0,stream>>>(din,rp,bsum,NN);
  scan3n<<<(NN+255)/256,256,0,stream>>>(rp,bsum,dout,din,csrc,cdst);
  scatk<<<(EE+255)/256,256,0,stream>>>(src,dst,rp,cur,ss);

  fgd1<<<512,512,0,stream>>>(nfb,rp,ss,Wg1,bg1,csrc,cdst,hpb);
  fgd2<<<512,512,0,stream>>>(hpb,rp,ss,Wg2,bg2,cdst,score);
}